// Round 3
// baseline (170.606 us; speedup 1.0000x reference)
//
#include <hip/hip_runtime.h>
#include <hip/hip_bf16.h>

// Problem constants (from setup_inputs): B=64,C=4 -> BF=256, N=1024, G=32, D=3, K=512
#define BFN   256
#define NPTS  1024
#define KSEL  512
#define GD    96          // G*D floats per patch row
#define ROW4  24          // GD/4 float4s per patch row (384 B)

__global__ __launch_bounds__(1024)
void crop_sampler_kernel(const float* __restrict__ patches,
                         const float* __restrict__ centers,
                         const int*   __restrict__ center_idx,
                         float* __restrict__ out_patches,
                         float* __restrict__ out_centers)
{
    __shared__ unsigned long long keys[NPTS];

    const int bf = blockIdx.x;
    const int t  = threadIdx.x;

    const float* cbase = centers + (size_t)bf * NPTS * 3;

    // query point (broadcast read, L1/L2 cached)
    const int qi = center_idx[bf];
    const float q0 = cbase[qi * 3 + 0];
    const float q1 = cbase[qi * 3 + 1];
    const float q2 = cbase[qi * 3 + 2];

    // my point
    const float c0 = cbase[t * 3 + 0];
    const float c1 = cbase[t * 3 + 1];
    const float c2 = cbase[t * 3 + 2];

    // d2 in DOUBLE: f32 diffs are exact in f64 (<=25 sig bits), squares exact
    // (<=50 bits), sum within 1 ulp f64 -> this is the TRUE ordering, matching
    // a higher-precision numpy reference. (Round-2 evidence: exact-f32 ordering
    // disagreed on ~45/131072 rows -> near-tie mismatches, so ref is not f32.)
    const double e0 = (double)q0 - (double)c0;
    const double e1 = (double)q1 - (double)c1;
    const double e2 = (double)q2 - (double)c2;
    const double d2 = e0 * e0 + e1 * e1 + e2 * e2;

    // sortable key: d2 >= 0 so the f64 bit pattern is monotone. Keep top 54
    // bits (44-bit mantissa precision, ~2^-44 relative — far below any real
    // d2 gap), put the index in the low 10 bits: ascending key == ascending
    // d2 with stable (lowest-index-first) tie-break, matching top_k.
    const unsigned long long bits = (unsigned long long)__double_as_longlong(d2);
    keys[t] = (bits & 0xFFFFFFFFFFFFFC00ull) | (unsigned long long)t;

    // bitonic sort, ascending, 1024 elements, 1024 threads (512 active pairs/step)
    for (int size = 2; size <= NPTS; size <<= 1) {
        for (int stride = size >> 1; stride > 0; stride >>= 1) {
            __syncthreads();
            const int partner = t ^ stride;
            if (partner > t) {
                const bool descending = (t & size) != 0;
                unsigned long long a = keys[t];
                unsigned long long b = keys[partner];
                const bool doswap = descending ? (a < b) : (a > b);
                if (doswap) { keys[t] = b; keys[partner] = a; }
            }
        }
    }
    __syncthreads();

    // ---- gather centers: K rows x 3 floats ----
    float* oc = out_centers + (size_t)bf * KSEL * 3;
    for (int i = t; i < KSEL * 3; i += 1024) {
        const int k = i / 3;
        const int d = i - k * 3;
        const int idx = (int)(keys[k] & 0x3FFu);
        oc[(size_t)k * 3 + d] = cbase[(size_t)idx * 3 + d];
    }

    // ---- gather patches: K rows x 24 float4 (384 B contiguous per row) ----
    const float4* pbase = (const float4*)(patches + (size_t)bf * NPTS * GD);
    float4*       op    = (float4*)(out_patches + (size_t)bf * KSEL * GD);
    for (int i = t; i < KSEL * ROW4; i += 1024) {
        const int k    = i / ROW4;
        const int lane = i - k * ROW4;
        const int idx  = (int)(keys[k] & 0x3FFu);
        op[(size_t)k * ROW4 + lane] = pbase[(size_t)idx * ROW4 + lane];
    }
}

extern "C" void kernel_launch(void* const* d_in, const int* in_sizes, int n_in,
                              void* d_out, int out_size, void* d_ws, size_t ws_size,
                              hipStream_t stream)
{
    const float* patches    = (const float*)d_in[0];
    const float* centers    = (const float*)d_in[1];
    const int*   center_idx = (const int*)d_in[2];
    // d_in[3] is K (=512), static-shaped; hardcoded as KSEL.

    float* out_patches = (float*)d_out;                           // BF*K*G*D floats
    float* out_centers = (float*)d_out + (size_t)BFN * KSEL * GD; // BF*K*D floats

    crop_sampler_kernel<<<BFN, 1024, 0, stream>>>(patches, centers, center_idx,
                                                  out_patches, out_centers);
}

// Round 4
// 167.721 us; speedup vs baseline: 1.0172x; 1.0172x over previous
//
#include <hip/hip_runtime.h>
#include <hip/hip_bf16.h>

// B=64,C=4 -> BF=256, N=1024, G=32, D=3, K=512
#define BFN   256
#define NPTS  1024
#define KSEL  512
#define GD    96          // G*D floats per patch row
#define ROW4  24          // GD/4 float4s per patch row (384 B)
#define PBLK  12288       // BFN*KSEL*ROW4 / 256 float4-gather blocks
#define CBLK  512         // BFN*KSEL / 256 center-row blocks

typedef unsigned long long u64;

// ---------------- selection: sorted top-K indices per bf ----------------
__global__ __launch_bounds__(1024)
void sel_kernel(const float* __restrict__ centers,
                const int*   __restrict__ center_idx,
                int* __restrict__ out_idx)
{
    __shared__ u64 lds[NPTS];
    const int bf = blockIdx.x;
    const int t  = threadIdx.x;

    const float* cbase = centers + (size_t)bf * NPTS * 3;
    const int qi = center_idx[bf];
    const float q0 = cbase[qi * 3 + 0], q1 = cbase[qi * 3 + 1], q2 = cbase[qi * 3 + 2];
    const float c0 = cbase[t * 3 + 0],  c1 = cbase[t * 3 + 1],  c2 = cbase[t * 3 + 2];

    // f64 d2 from f32 inputs is exact (<=25-bit diffs, <=50-bit squares):
    // true mathematical ordering -> matches numpy ref (round-3 verified, absmax 0).
    const double e0 = (double)q0 - (double)c0;
    const double e1 = (double)q1 - (double)c1;
    const double e2 = (double)q2 - (double)c2;
    const double d2 = e0 * e0 + e1 * e1 + e2 * e2;

    // d2>=0 -> f64 bits monotone; low 10 bits = index (stable tie-break).
    u64 key = (((u64)__double_as_longlong(d2)) & ~0x3FFull) | (u64)t;

    // bitonic sort, 1024 keys, one per thread.
    // strides <=32: in-wave shfl_xor (register-resident, no barrier) - 45 steps
    // strides >=64: LDS + 2 barriers - 10 steps
    for (int size = 2; size <= NPTS; size <<= 1) {
        const bool dir = (t & size) != 0;     // size=1024 -> always ascending
        for (int stride = size >> 1; stride > 0; stride >>= 1) {
            u64 other;
            if (stride >= 64) {
                __syncthreads();
                lds[t] = key;
                __syncthreads();
                other = lds[t ^ stride];
            } else {
                other = __shfl_xor(key, stride, 64);
            }
            const bool upper    = (t & stride) != 0;
            const bool keep_min = (upper == dir);
            const bool mine_lt  = key < other;        // keys unique
            key = (keep_min == mine_lt) ? key : other;
        }
    }

    if (t < KSEL) out_idx[bf * KSEL + t] = (int)(key & 0x3FFull);
}

// ---------------- gather: one float4 (or one center row) per thread ----------------
__global__ __launch_bounds__(256)
void gather_kernel(const float* __restrict__ patches,
                   const float* __restrict__ centers,
                   const int*   __restrict__ idx,
                   float* __restrict__ out_p,
                   float* __restrict__ out_c)
{
    const int b = blockIdx.x;
    const int t = threadIdx.x;
    if (b < PBLK) {
        const int i    = b * 256 + t;        // float4 index < BFN*KSEL*ROW4
        const int row  = i / ROW4;           // output row in [0, BFN*KSEL)
        const int lane = i - row * ROW4;
        const int bf   = row >> 9;           // row / KSEL
        const int src  = idx[row];           // 0..1023 (L1-broadcast across ~11 rows/block)
        const float4* pb = (const float4*)patches;
        float4 v = pb[((size_t)bf * NPTS + src) * ROW4 + lane];
        ((float4*)out_p)[(size_t)row * ROW4 + lane] = v;
    } else {
        const int r  = (b - PBLK) * 256 + t; // output row in [0, BFN*KSEL)
        const int bf = r >> 9;
        const int src = idx[r];
        const float* cb = centers + ((size_t)bf * NPTS + src) * 3;
        float* oc = out_c + (size_t)r * 3;
        oc[0] = cb[0]; oc[1] = cb[1]; oc[2] = cb[2];
    }
}

extern "C" void kernel_launch(void* const* d_in, const int* in_sizes, int n_in,
                              void* d_out, int out_size, void* d_ws, size_t ws_size,
                              hipStream_t stream)
{
    const float* patches    = (const float*)d_in[0];
    const float* centers    = (const float*)d_in[1];
    const int*   center_idx = (const int*)d_in[2];
    // d_in[3] is K (=512), static; hardcoded as KSEL.

    float* out_patches = (float*)d_out;                           // BF*K*G*D
    float* out_centers = (float*)d_out + (size_t)BFN * KSEL * GD; // BF*K*D
    int*   idx_ws      = (int*)d_ws;                              // BF*K ints = 512 KB (ws ~400 MB)

    sel_kernel<<<BFN, 1024, 0, stream>>>(centers, center_idx, idx_ws);
    gather_kernel<<<PBLK + CBLK, 256, 0, stream>>>(patches, centers, idx_ws,
                                                   out_patches, out_centers);
}